// Round 2
// baseline (254.282 us; speedup 1.0000x reference)
//
#include <hip/hip_runtime.h>

// Problem constants (fixed by the reference file)
#define SEQ   3456
#define DH    32
#define FPT   216        // feats_per_t
#define WLEN  8
#define IMG0  20         // FPT - img_feat_size(196): first img feature index
#define SCALE 0.17677669529663687f   // 1/sqrt(32)

// Mask recap (derived from eye_mask):
//  same-t: all 216 keys visible EXCEPT img->img  => img queries see only j<20;
//          non-img queries (qm<20) additionally see j=20..215 (kernel B).
//  past (1..7 back): only j<20 ever visible; j==4 (proprio) masked;
//          joint queries (4<=qm<20) additionally masked for j in [4,20).

// ---------------- Kernel A: main, 2-way key split, no LDS ----------------
// split 0: same-t j<20  + past d=1..3   (raw acc -> d_out, l -> ws[l0])
// split 1: past d=4..7                  (raw acc -> ws[acc1], l -> ws[l1])
__global__ __launch_bounds__(256)
void eye_attn_main(const float* __restrict__ q, const float* __restrict__ k,
                   const float* __restrict__ v, float* __restrict__ outacc,
                   float* __restrict__ ws, long l0_off, long l1_off) {
    const int  split = blockIdx.y;
    const unsigned qg = blockIdx.x * 256u + threadIdx.x;   // global query id
    const unsigned bh = qg / (unsigned)SEQ;
    const unsigned s  = qg % (unsigned)SEQ;
    const unsigned t  = s / (unsigned)FPT;
    const unsigned qm = s % (unsigned)FPT;
    const bool qj = (qm >= 4u) && (qm < 20u);              // joint query
    const size_t base = (size_t)bh * SEQ * DH;

    const float4* qp = (const float4*)(q + base + (size_t)s * DH);
    float4 qr[8];
    #pragma unroll
    for (int i = 0; i < 8; ++i) {
        float4 x = qp[i];
        x.x *= SCALE; x.y *= SCALE; x.z *= SCALE; x.w *= SCALE;
        qr[i] = x;
    }
    float4 acc[8];
    #pragma unroll
    for (int i = 0; i < 8; ++i) acc[i] = make_float4(0.f, 0.f, 0.f, 0.f);
    float l = 0.f;

    const int dlo = split ? 4 : 0;
    const int dhi = split ? 7 : 3;
    for (int d = dlo; d <= dhi; ++d) {
        const int  kt  = (int)t - d;
        const bool blk = (kt >= 0);
        if (__ballot(blk) == 0ull) continue;   // whole wave out of window
        const int ktc = blk ? kt : 0;
        const float4* kb = (const float4*)(k + base + (size_t)ktc * FPT * DH);
        const float4* vb = (const float4*)(v + base + (size_t)ktc * FPT * DH);
        const bool same = (d == 0);
        #pragma unroll 2
        for (int j = 0; j < IMG0; ++j) {
            const float4* kr = kb + j * (DH / 4);
            float s0 = 0.f, s1 = 0.f, s2 = 0.f, s3 = 0.f;
            #pragma unroll
            for (int i = 0; i < 8; ++i) {
                float4 kk = kr[i];
                s0 = fmaf(qr[i].x, kk.x, s0);
                s1 = fmaf(qr[i].y, kk.y, s1);
                s2 = fmaf(qr[i].z, kk.z, s2);
                s3 = fmaf(qr[i].w, kk.w, s3);
            }
            const float sd = (s0 + s1) + (s2 + s3);
            const bool vis = blk && (same || (j < 4) || (j > 4 && !qj));
            const float e = vis ? __expf(sd) : 0.f;
            l += e;
            const float4* vr = vb + j * (DH / 4);
            #pragma unroll
            for (int i = 0; i < 8; ++i) {
                float4 vv = vr[i];
                acc[i].x = fmaf(e, vv.x, acc[i].x);
                acc[i].y = fmaf(e, vv.y, acc[i].y);
                acc[i].z = fmaf(e, vv.z, acc[i].z);
                acc[i].w = fmaf(e, vv.w, acc[i].w);
            }
        }
    }

    if (split == 0) {
        float4* op = (float4*)outacc + (size_t)qg * 8;
        #pragma unroll
        for (int i = 0; i < 8; ++i) op[i] = acc[i];
        ws[l0_off + qg] = l;
    } else {
        float4* ap = (float4*)ws + (size_t)qg * 8;
        #pragma unroll
        for (int i = 0; i < 8; ++i) ap[i] = acc[i];
        ws[l1_off + qg] = l;
    }
}

// ------- Kernel B: non-img queries (qm<20) x same-t img keys (j=20..215) -------
// One wave per query; lane-parallel over keys; butterfly-reduce (l, acc[32]).
__global__ __launch_bounds__(256)
void eye_attn_imgk(const float* __restrict__ q, const float* __restrict__ k,
                   const float* __restrict__ v, float* __restrict__ ws,
                   long bacc_off, long bl_off) {
    const unsigned gid  = blockIdx.x * 256u + threadIdx.x;
    const unsigned wid  = gid >> 6;          // query id 0 .. BH*16*20-1
    const unsigned lane = gid & 63u;
    const unsigned bh = wid / 320u;
    const unsigned r  = wid % 320u;
    const unsigned t  = r / 20u;
    const unsigned qm = r % 20u;
    const size_t base = (size_t)bh * SEQ * DH;
    const unsigned srow = t * FPT + qm;

    const float4* qp = (const float4*)(q + base + (size_t)srow * DH);
    float4 qr[8];
    #pragma unroll
    for (int i = 0; i < 8; ++i) {
        float4 x = qp[i];
        x.x *= SCALE; x.y *= SCALE; x.z *= SCALE; x.w *= SCALE;
        qr[i] = x;
    }
    float4 acc[8];
    #pragma unroll
    for (int i = 0; i < 8; ++i) acc[i] = make_float4(0.f, 0.f, 0.f, 0.f);
    float l = 0.f;

    #pragma unroll
    for (int i = 0; i < 4; ++i) {
        const int j = IMG0 + (int)lane + 64 * i;   // 196 img keys over 64 lanes
        if (j < FPT) {
            const float4* kr = (const float4*)(k + base + (size_t)(t * FPT + j) * DH);
            float s0 = 0.f, s1 = 0.f, s2 = 0.f, s3 = 0.f;
            #pragma unroll
            for (int ii = 0; ii < 8; ++ii) {
                float4 kk = kr[ii];
                s0 = fmaf(qr[ii].x, kk.x, s0);
                s1 = fmaf(qr[ii].y, kk.y, s1);
                s2 = fmaf(qr[ii].z, kk.z, s2);
                s3 = fmaf(qr[ii].w, kk.w, s3);
            }
            const float e = __expf((s0 + s1) + (s2 + s3));
            l += e;
            const float4* vr = (const float4*)(v + base + (size_t)(t * FPT + j) * DH);
            #pragma unroll
            for (int ii = 0; ii < 8; ++ii) {
                float4 vv = vr[ii];
                acc[ii].x = fmaf(e, vv.x, acc[ii].x);
                acc[ii].y = fmaf(e, vv.y, acc[ii].y);
                acc[ii].z = fmaf(e, vv.z, acc[ii].z);
                acc[ii].w = fmaf(e, vv.w, acc[ii].w);
            }
        }
    }

    // 64-lane butterfly reduction of l and acc[32]
    #pragma unroll
    for (int off = 32; off >= 1; off >>= 1) {
        l += __shfl_xor(l, off);
        #pragma unroll
        for (int i = 0; i < 8; ++i) {
            acc[i].x += __shfl_xor(acc[i].x, off);
            acc[i].y += __shfl_xor(acc[i].y, off);
            acc[i].z += __shfl_xor(acc[i].z, off);
            acc[i].w += __shfl_xor(acc[i].w, off);
        }
    }
    if (lane == 0) {
        float4* bp = (float4*)(ws + bacc_off) + (size_t)wid * 8;
        #pragma unroll
        for (int i = 0; i < 8; ++i) bp[i] = acc[i];
        ws[bl_off + wid] = l;
    }
}

// ---------------- Kernel C: combine & normalize ----------------
// thread = one float4 chunk of one query's output (8 threads / query)
__global__ __launch_bounds__(256)
void eye_attn_combine(float* __restrict__ out, const float* __restrict__ ws,
                      long l0_off, long l1_off, long bacc_off, long bl_off) {
    const unsigned gid = blockIdx.x * 256u + threadIdx.x;
    const unsigned qg  = gid >> 3;
    const unsigned c   = gid & 7u;
    const unsigned s   = qg % (unsigned)SEQ;
    const unsigned qm  = s % (unsigned)FPT;

    float l = ws[l0_off + qg] + ws[l1_off + qg];
    float4 a = ((const float4*)out)[(size_t)qg * 8 + c];
    float4 b = ((const float4*)ws)[(size_t)qg * 8 + c];
    a.x += b.x; a.y += b.y; a.z += b.z; a.w += b.w;

    if (qm < IMG0) {
        const unsigned bh = qg / (unsigned)SEQ;
        const unsigned t  = s / (unsigned)FPT;
        const unsigned wid = bh * 320u + t * 20u + qm;
        float4 bb = ((const float4*)(ws + bacc_off))[(size_t)wid * 8 + c];
        a.x += bb.x; a.y += bb.y; a.z += bb.z; a.w += bb.w;
        l += ws[bl_off + wid];
    }
    const float inv = 1.f / l;
    a.x *= inv; a.y *= inv; a.z *= inv; a.w *= inv;
    ((float4*)out)[(size_t)qg * 8 + c] = a;
}

extern "C" void kernel_launch(void* const* d_in, const int* in_sizes, int n_in,
                              void* d_out, int out_size, void* d_ws, size_t ws_size,
                              hipStream_t stream) {
    const float* q = (const float*)d_in[0];
    const float* k = (const float*)d_in[1];
    const float* v = (const float*)d_in[2];
    float* out = (float*)d_out;
    float* ws  = (float*)d_ws;

    const int BH     = in_sizes[0] / (SEQ * DH);     // 24
    const long totq  = (long)BH * SEQ;               // 82944
    const long nspec = (long)BH * 16 * 20;           // 7680

    // ws float layout: [acc1: totq*32][l0: totq][l1: totq][Bacc: nspec*32][Bl: nspec]
    const long l0_off   = totq * 32;
    const long l1_off   = l0_off + totq;
    const long bacc_off = l1_off + totq;
    const long bl_off   = bacc_off + nspec * 32;
    // total = totq*34 + nspec*33 floats ~= 12.3 MB

    dim3 gridA((unsigned)(totq / 256), 2);
    eye_attn_main<<<gridA, 256, 0, stream>>>(q, k, v, out, ws, l0_off, l1_off);

    dim3 gridB((unsigned)(nspec * 64 / 256));
    eye_attn_imgk<<<gridB, 256, 0, stream>>>(q, k, v, ws, bacc_off, bl_off);

    dim3 gridC((unsigned)(totq * 8 / 256));
    eye_attn_combine<<<gridC, 256, 0, stream>>>(out, ws, l0_off, l1_off,
                                                bacc_off, bl_off);
}

// Round 3
// 180.418 us; speedup vs baseline: 1.4094x; 1.4094x over previous
//
#include <hip/hip_runtime.h>

// Problem constants (fixed by the reference file)
#define SEQ   3456
#define DH    32
#define FPT   216        // feats_per_t
#define NT    16         // SEQ/FPT
#define IMG0  20         // first img feature index (FPT-196)
#define SCALE 0.17677669529663687f   // 1/sqrt(32)

// Visibility (derived from eye_mask, verified rounds 1-2):
//  same-t: all 216 keys visible except img->img
//          => every query sees j<20; non-img queries (qm<20) also see j=20..215
//  past (1..7 back): only j<20 ever visible; j==4 masked for all;
//          joint queries (4<=qm<20) see only j<4; others see j!=4.

__global__ __launch_bounds__(256)
void eye_attn_fused(const float* __restrict__ q, const float* __restrict__ k,
                    const float* __restrict__ v, float* __restrict__ out) {
    const int t   = blockIdx.x;
    const int bh  = blockIdx.y;
    const int tid = threadIdx.x;
    const size_t base = (size_t)bh * SEQ * DH;
    const int dmax = (t < 7) ? t : 7;
    const int nrow = IMG0 * (dmax + 1);         // 20..160 staged rows

    // 40 KB: [Kl: 160 rows x 32][Vl: 160 rows x 32]; region reused for
    // phase-B partials (240 x 33 floats) after phase A finishes.
    __shared__ float smem[2 * 8 * IMG0 * DH];
    float* Kl = smem;
    float* Vl = smem + 8 * IMG0 * DH;

    // ---- stage small K/V rows: for d=0..dmax, rows (t-d)*FPT+0..19 ----
    {
        const int nf4 = nrow * (DH / 4);        // up to 1280 float4 per array
        for (int i = tid; i < nf4; i += 256) {
            const int d = i / (IMG0 * DH / 4);  // chunk (160 float4 each)
            const int r = i - d * (IMG0 * DH / 4);
            const float4* kg = (const float4*)(k + base + (size_t)(t - d) * FPT * DH);
            const float4* vg = (const float4*)(v + base + (size_t)(t - d) * FPT * DH);
            ((float4*)Kl)[i] = kg[r];
            ((float4*)Vl)[i] = vg[r];
        }
    }
    __syncthreads();

    // ---- Phase A: thread = query, uniform 20*(dmax+1) key-iters ----
    const int  qm      = tid;
    const bool activeA = qm < FPT;
    const bool qj      = (qm >= 4) && (qm < IMG0);
    float4 qr[8], acc[8];
    float  l = 0.f;
    if (activeA) {
        const float4* qp = (const float4*)(q + base + (size_t)(t * FPT + qm) * DH);
        #pragma unroll
        for (int i = 0; i < 8; ++i) {
            float4 x = qp[i];
            x.x *= SCALE; x.y *= SCALE; x.z *= SCALE; x.w *= SCALE;
            qr[i] = x;
            acc[i] = make_float4(0.f, 0.f, 0.f, 0.f);
        }
        const unsigned visPast = qj ? 0x0000Fu : 0xFFFEFu;  // 20-bit mask
        for (int d = 0; d <= dmax; ++d) {
            const unsigned vm = (d == 0) ? 0xFFFFFu : visPast;
            const float* Kb = Kl + d * IMG0 * DH;
            const float* Vb = Vl + d * IMG0 * DH;
            #pragma unroll 4
            for (int j = 0; j < IMG0; ++j) {
                const float4* kr = (const float4*)(Kb + j * DH);
                float s0 = 0.f, s1 = 0.f, s2 = 0.f, s3 = 0.f;
                #pragma unroll
                for (int i = 0; i < 8; ++i) {
                    float4 kk = kr[i];
                    s0 = fmaf(qr[i].x, kk.x, s0);
                    s1 = fmaf(qr[i].y, kk.y, s1);
                    s2 = fmaf(qr[i].z, kk.z, s2);
                    s3 = fmaf(qr[i].w, kk.w, s3);
                }
                const float e = ((vm >> j) & 1u) ? __expf((s0 + s1) + (s2 + s3)) : 0.f;
                l += e;
                const float4* vr = (const float4*)(Vb + j * DH);
                #pragma unroll
                for (int i = 0; i < 8; ++i) {
                    float4 vv = vr[i];
                    acc[i].x = fmaf(e, vv.x, acc[i].x);
                    acc[i].y = fmaf(e, vv.y, acc[i].y);
                    acc[i].z = fmaf(e, vv.z, acc[i].z);
                    acc[i].w = fmaf(e, vv.w, acc[i].w);
                }
            }
        }
    }
    __syncthreads();   // all phase-A LDS reads done; smem now reusable

    // ---- Phase B: 20 non-img queries x 196 same-t img keys, 240 threads ----
    // thread tid = bq*12 + c; chunks 0..3 have 17 keys, 4..11 have 16.
    if (tid < 240) {
        const int bq = tid / 12;
        const int c  = tid - bq * 12;
        const int j0 = (c < 4) ? (IMG0 + c * 17) : (IMG0 + 68 + (c - 4) * 16);
        const int nj = (c < 4) ? 17 : 16;
        const float4* qp = (const float4*)(q + base + (size_t)(t * FPT + bq) * DH);
        float4 qb[8], ab[8];
        #pragma unroll
        for (int i = 0; i < 8; ++i) {
            float4 x = qp[i];
            x.x *= SCALE; x.y *= SCALE; x.z *= SCALE; x.w *= SCALE;
            qb[i] = x;
            ab[i] = make_float4(0.f, 0.f, 0.f, 0.f);
        }
        float lb = 0.f;
        for (int jj = 0; jj < nj; ++jj) {
            const size_t row = base + (size_t)(t * FPT + j0 + jj) * DH;
            const float4* kr = (const float4*)(k + row);
            float s0 = 0.f, s1 = 0.f, s2 = 0.f, s3 = 0.f;
            #pragma unroll
            for (int i = 0; i < 8; ++i) {
                float4 kk = kr[i];
                s0 = fmaf(qb[i].x, kk.x, s0);
                s1 = fmaf(qb[i].y, kk.y, s1);
                s2 = fmaf(qb[i].z, kk.z, s2);
                s3 = fmaf(qb[i].w, kk.w, s3);
            }
            const float e = __expf((s0 + s1) + (s2 + s3));
            lb += e;
            const float4* vr = (const float4*)(v + row);
            #pragma unroll
            for (int i = 0; i < 8; ++i) {
                float4 vv = vr[i];
                ab[i].x = fmaf(e, vv.x, ab[i].x);
                ab[i].y = fmaf(e, vv.y, ab[i].y);
                ab[i].z = fmaf(e, vv.z, ab[i].z);
                ab[i].w = fmaf(e, vv.w, ab[i].w);
            }
        }
        // partial -> LDS, stride 33 (conflict-free: gcd(33,32)=1)
        float* p = smem + tid * 33;
        p[0] = lb;
        #pragma unroll
        for (int i = 0; i < 8; ++i) {
            p[1 + 4 * i] = ab[i].x; p[2 + 4 * i] = ab[i].y;
            p[3 + 4 * i] = ab[i].z; p[4 + 4 * i] = ab[i].w;
        }
    }
    __syncthreads();

    // ---- merge + normalize + store ----
    if (activeA) {
        if (qm < IMG0) {
            for (int c = 0; c < 12; ++c) {
                const float* p = smem + (qm * 12 + c) * 33;
                l += p[0];
                #pragma unroll
                for (int i = 0; i < 8; ++i) {
                    acc[i].x += p[1 + 4 * i]; acc[i].y += p[2 + 4 * i];
                    acc[i].z += p[3 + 4 * i]; acc[i].w += p[4 + 4 * i];
                }
            }
        }
        const float inv = 1.f / l;
        float4* op = (float4*)(out + base + (size_t)(t * FPT + qm) * DH);
        #pragma unroll
        for (int i = 0; i < 8; ++i) {
            float4 r = acc[i];
            r.x *= inv; r.y *= inv; r.z *= inv; r.w *= inv;
            op[i] = r;
        }
    }
}

extern "C" void kernel_launch(void* const* d_in, const int* in_sizes, int n_in,
                              void* d_out, int out_size, void* d_ws, size_t ws_size,
                              hipStream_t stream) {
    const float* q = (const float*)d_in[0];
    const float* k = (const float*)d_in[1];
    const float* v = (const float*)d_in[2];
    float* out = (float*)d_out;
    const int BH = in_sizes[0] / (SEQ * DH);   // 24
    dim3 grid(NT, BH);
    eye_attn_fused<<<grid, 256, 0, stream>>>(q, k, v, out);
}